// Round 1
// baseline (1135.794 us; speedup 1.0000x reference)
//
#include <hip/hip_runtime.h>

#define CC    64
#define HH    3
#define ECC   32
#define HCdim 192
#define NEG_SLOPE 0.2f

// ---- float <-> monotone uint key (for atomicMax on floats) ----
__device__ __forceinline__ unsigned fkey(float f) {
    int i = __float_as_int(f);
    return (i < 0) ? ~((unsigned)i) : (((unsigned)i) | 0x80000000u);
}
__device__ __forceinline__ float funkey(unsigned k) {
    int i = (k & 0x80000000u) ? (int)(k ^ 0x80000000u) : ~((int)k);
    return __int_as_float(i);
}

// K0: u[h*32+k] = sum_c We[k*192 + h*64 + c] * wt[h*192 + 64 + c]
__global__ void tm_k0(const float* __restrict__ We, const float* __restrict__ wt,
                      float* __restrict__ u) {
    int t = threadIdx.x;
    if (t >= HH * ECC) return;
    int h = t >> 5, k = t & 31;
    float s = 0.f;
    #pragma unroll
    for (int c = 0; c < CC; ++c)
        s = fmaf(We[k * HCdim + h * CC + c], wt[h * HCdim + CC + c], s);
    u[t] = s;
}

// K1: xp = x @ Wn  (50000x64 @ 64x192), fused per-node attention scalars:
//     sA[n*8+h]   = xp[n,h,:] . w0[h]   (x_i part, keyed by dst)
//     sA[n*8+4+h] = xp[n,h,:] . w2[h]   (x_j part, keyed by src)
#define K1_ROWS 64
__global__ __launch_bounds__(192) void tm_k1(const float* __restrict__ x,
        const float* __restrict__ Wn, const float* __restrict__ wt,
        float* __restrict__ xp, float* __restrict__ sA, int N) {
    __shared__ float wl[CC * HCdim];     // 48 KiB
    __shared__ float xl[K1_ROWS * CC];   // 16 KiB
    const int t = threadIdx.x;
    const int h = t >> 6, c = t & 63;
    for (int i = t; i < CC * HCdim; i += 192) wl[i] = Wn[i];
    const float w0c = wt[h * HCdim + c];
    const float w2c = wt[h * HCdim + 2 * CC + c];
    const int base = blockIdx.x * K1_ROWS;
    const int rows = min(K1_ROWS, N - base);
    for (int i = t; i < rows * CC; i += 192) xl[i] = x[(size_t)base * CC + i];
    __syncthreads();
    for (int r = 0; r < rows; ++r) {
        float v = 0.f;
        #pragma unroll
        for (int k = 0; k < CC; ++k)
            v = fmaf(xl[r * CC + k], wl[k * HCdim + t], v);
        const int n = base + r;
        xp[(size_t)n * HCdim + t] = v;
        float a0 = v * w0c, a2 = v * w2c;
        #pragma unroll
        for (int off = 32; off; off >>= 1) {
            a0 += __shfl_xor(a0, off);
            a2 += __shfl_xor(a2, off);
        }
        if (c == 0) {
            sA[n * 8 + h]     = a0;
            sA[n * 8 + 4 + h] = a2;
        }
    }
}

// K2: one thread per edge.
//     alpha[e,h] = leaky(s0[dst,h] + ea[e].u[h] + s2[src,h]); atomicMax segmax[dst,h]
__global__ __launch_bounds__(256) void tm_k2(const int* __restrict__ ei,
        const float* __restrict__ ea, const float* __restrict__ u,
        const float* __restrict__ sA, float* __restrict__ alpha,
        unsigned* __restrict__ segmax, int E) {
    __shared__ float ul[HH * ECC];
    const int t = threadIdx.x;
    if (t < HH * ECC) ul[t] = u[t];
    __syncthreads();
    for (int e = blockIdx.x * 256 + t; e < E; e += gridDim.x * 256) {
        const int src = ei[e];
        const int dst = ei[E + e];
        float av[ECC];
        const float4* p4 = (const float4*)(ea + (size_t)e * ECC);
        #pragma unroll
        for (int q = 0; q < 8; ++q) {
            float4 v = p4[q];
            av[4*q] = v.x; av[4*q+1] = v.y; av[4*q+2] = v.z; av[4*q+3] = v.w;
        }
        float d0 = 0.f, d1 = 0.f, d2 = 0.f;
        #pragma unroll
        for (int k = 0; k < ECC; ++k) {
            d0 = fmaf(av[k], ul[k], d0);
            d1 = fmaf(av[k], ul[ECC + k], d1);
            d2 = fmaf(av[k], ul[2 * ECC + k], d2);
        }
        const float4 s0 = *(const float4*)(sA + (size_t)dst * 8);
        const float4 s2 = *(const float4*)(sA + (size_t)src * 8 + 4);
        float a0 = s0.x + d0 + s2.x;
        float a1 = s0.y + d1 + s2.y;
        float a2 = s0.z + d2 + s2.z;
        a0 = (a0 >= 0.f) ? a0 : NEG_SLOPE * a0;
        a1 = (a1 >= 0.f) ? a1 : NEG_SLOPE * a1;
        a2 = (a2 >= 0.f) ? a2 : NEG_SLOPE * a2;
        alpha[(size_t)e * 3 + 0] = a0;
        alpha[(size_t)e * 3 + 1] = a1;
        alpha[(size_t)e * 3 + 2] = a2;
        atomicMax(&segmax[dst * 3 + 0], fkey(a0));
        atomicMax(&segmax[dst * 3 + 1], fkey(a1));
        atomicMax(&segmax[dst * 3 + 2], fkey(a2));
    }
}

// K4: one wave per (edge, head); head fixed per wave so We column lives in regs.
//     p = exp(alpha - segmax[dst]); segsum[dst,h] += p (lane 0);
//     aggr[dst, h*64+lane] += p * ep[lane] * xp[src, h*64+lane]   (unnormalized)
__global__ __launch_bounds__(256) void tm_k4(const int* __restrict__ ei,
        const float* __restrict__ ea, const float* __restrict__ We,
        const float* __restrict__ xp, const float* __restrict__ alpha,
        const unsigned* __restrict__ segmax, float* __restrict__ segsum,
        float* __restrict__ aggr, int E, int estride) {
    const int t = threadIdx.x;
    const int lane = t & 63;
    const int w = blockIdx.x * 4 + (t >> 6);   // global wave id, grid gives 7500 waves
    const int h = w % 3;                       // fixed per wave across the e-loop
    float wcol[ECC];
    #pragma unroll
    for (int k = 0; k < ECC; ++k)
        wcol[k] = We[k * HCdim + h * CC + lane];
    for (int e = w / 3; e < E; e += estride) {
        const int src = ei[e];
        const int dst = ei[E + e];
        const float ar = alpha[(size_t)e * 3 + h];
        const float m  = funkey(segmax[dst * 3 + h]);
        const float p  = __expf(ar - m);
        if (lane == 0) atomicAdd(&segsum[dst * 3 + h], p);
        float av[ECC];
        const float4* p4 = (const float4*)(ea + (size_t)e * ECC);
        #pragma unroll
        for (int q = 0; q < 8; ++q) {
            float4 v = p4[q];
            av[4*q] = v.x; av[4*q+1] = v.y; av[4*q+2] = v.z; av[4*q+3] = v.w;
        }
        float ep = 0.f;
        #pragma unroll
        for (int k = 0; k < ECC; ++k)
            ep = fmaf(av[k], wcol[k], ep);
        const float xj = xp[(size_t)src * HCdim + h * CC + lane];
        atomicAdd(&aggr[(size_t)dst * HCdim + h * CC + lane], p * ep * xj);
    }
}

// K5: out[n,:] = (aggr[n,:] / (segsum[n,h]+1e-16)) @ Ws + bias
__global__ __launch_bounds__(256) void tm_k5(const float* __restrict__ aggr,
        const float* __restrict__ segsum, const float* __restrict__ Ws,
        const float* __restrict__ bias, float* __restrict__ out, int N) {
    __shared__ float wsl[HCdim * CC];   // 48 KiB
    __shared__ float al[4][HCdim];
    const int t = threadIdx.x;
    const int wv = t >> 6, lane = t & 63;
    for (int i = t; i < HCdim * CC; i += 256) wsl[i] = Ws[i];
    const float b = bias[lane];
    for (int base = blockIdx.x * 4; base < N; base += gridDim.x * 4) {
        const int n = base + wv;
        __syncthreads();
        if (n < N) {
            const float i0 = 1.f / (segsum[n * 3 + 0] + 1e-16f);
            const float i1 = 1.f / (segsum[n * 3 + 1] + 1e-16f);
            const float i2 = 1.f / (segsum[n * 3 + 2] + 1e-16f);
            al[wv][lane]          = aggr[(size_t)n * HCdim + lane] * i0;
            al[wv][CC + lane]     = aggr[(size_t)n * HCdim + CC + lane] * i1;
            al[wv][2 * CC + lane] = aggr[(size_t)n * HCdim + 2 * CC + lane] * i2;
        }
        __syncthreads();
        if (n < N) {
            float acc = b;
            #pragma unroll
            for (int k = 0; k < HCdim; ++k)
                acc = fmaf(al[wv][k], wsl[k * CC + lane], acc);
            out[(size_t)n * CC + lane] = acc;
        }
    }
}

extern "C" void kernel_launch(void* const* d_in, const int* in_sizes, int n_in,
                              void* d_out, int out_size, void* d_ws, size_t ws_size,
                              hipStream_t stream) {
    const float* x    = (const float*)d_in[0];
    const int*   ei   = (const int*)d_in[1];
    const float* ea   = (const float*)d_in[2];
    const float* Wn   = (const float*)d_in[3];
    const float* We   = (const float*)d_in[4];
    const float* wt   = (const float*)d_in[5];
    const float* Ws   = (const float*)d_in[6];
    const float* bias = (const float*)d_in[7];
    float* out = (float*)d_out;
    const int N = in_sizes[0] / CC;
    const int E = in_sizes[1] / 2;

    // workspace layout (floats)
    float* ws = (float*)d_ws;
    size_t o = 0;
    float* xp = ws + o;                 o += (size_t)N * HCdim;   // 38.4 MB
    float* sA = ws + o;                 o += (size_t)N * 8;       // 1.6 MB
    float* u  = ws + o;                 o += 128;
    float* alpha = ws + o;              o += (size_t)E * HH;      // 9.6 MB
    unsigned* segmax = (unsigned*)(ws + o); o += (size_t)N * HH;  // 0.6 MB
    float* segsum = ws + o;             o += (size_t)N * HH;      // 0.6 MB
    float* aggr = ws + o;               o += (size_t)N * HCdim;   // 38.4 MB
    (void)ws_size; (void)n_in; (void)out_size;

    // zero the accumulated buffers (segmax, segsum, aggr are contiguous)
    hipMemsetAsync(segmax, 0,
                   ((size_t)N * HH * 2 + (size_t)N * HCdim) * sizeof(float),
                   stream);

    tm_k0<<<1, 96, 0, stream>>>(We, wt, u);
    tm_k1<<<(N + K1_ROWS - 1) / K1_ROWS, 192, 0, stream>>>(x, Wn, wt, xp, sA, N);
    tm_k2<<<(E + 255) / 256, 256, 0, stream>>>(ei, ea, u, sA, alpha, segmax, E);
    const int blocks4 = 1875;                 // 7500 waves, divisible by 3 heads
    const int estride = blocks4 * 4 / 3;      // 2500 edges per head-wave stride
    tm_k4<<<blocks4, 256, 0, stream>>>(ei, ea, We, xp, alpha, segmax, segsum,
                                       aggr, E, estride);
    tm_k5<<<2048, 256, 0, stream>>>(aggr, segsum, Ws, bias, out, N);
}

// Round 2
// 629.015 us; speedup vs baseline: 1.8057x; 1.8057x over previous
//
#include <hip/hip_runtime.h>

#define CC    64
#define HH    3
#define ECC   32
#define HCdim 192
#define NEG_SLOPE 0.2f

// K0: u[h*32+k] = sum_c We[k*192 + h*64 + c] * wt[h*192 + 64 + c]
__global__ void tm_k0(const float* __restrict__ We, const float* __restrict__ wt,
                      float* __restrict__ u) {
    int t = threadIdx.x;
    if (t >= HH * ECC) return;
    int h = t >> 5, k = t & 31;
    float s = 0.f;
    #pragma unroll
    for (int c = 0; c < CC; ++c)
        s = fmaf(We[k * HCdim + h * CC + c], wt[h * HCdim + CC + c], s);
    u[t] = s;
}

// K1: xp = x @ Wn (N x 64 @ 64 x 192), fused per-node attention scalars:
//     sA[n*8+h]   = xp[n,h,:] . w0[h]   (x_i part, keyed by dst)
//     sA[n*8+4+h] = xp[n,h,:] . w2[h]   (x_j part, keyed by src)
#define K1_ROWS 64
__global__ __launch_bounds__(192) void tm_k1(const float* __restrict__ x,
        const float* __restrict__ Wn, const float* __restrict__ wt,
        float* __restrict__ xp, float* __restrict__ sA, int N) {
    __shared__ float wl[CC * HCdim];     // 48 KiB
    __shared__ float xl[K1_ROWS * CC];   // 16 KiB
    const int t = threadIdx.x;
    const int h = t >> 6, c = t & 63;
    for (int i = t; i < CC * HCdim; i += 192) wl[i] = Wn[i];
    const float w0c = wt[h * HCdim + c];
    const float w2c = wt[h * HCdim + 2 * CC + c];
    const int base = blockIdx.x * K1_ROWS;
    const int rows = min(K1_ROWS, N - base);
    for (int i = t; i < rows * CC; i += 192) xl[i] = x[(size_t)base * CC + i];
    __syncthreads();
    for (int r = 0; r < rows; ++r) {
        float v = 0.f;
        #pragma unroll
        for (int k = 0; k < CC; ++k)
            v = fmaf(xl[r * CC + k], wl[k * HCdim + t], v);
        const int n = base + r;
        xp[(size_t)n * HCdim + t] = v;
        float a0 = v * w0c, a2 = v * w2c;
        #pragma unroll
        for (int off = 32; off; off >>= 1) {
            a0 += __shfl_xor(a0, off);
            a2 += __shfl_xor(a2, off);
        }
        if (c == 0) {
            sA[n * 8 + h]     = a0;
            sA[n * 8 + 4 + h] = a2;
        }
    }
}

// K_deg: degree histogram over dst
__global__ __launch_bounds__(256) void tm_deg(const int* __restrict__ ei,
        int* __restrict__ deg, int E) {
    int e = blockIdx.x * 256 + threadIdx.x;
    if (e < E) atomicAdd(&deg[ei[E + e]], 1);
}

// scanA: per-block (256) sums of deg
__global__ __launch_bounds__(256) void tm_scanA(const int* __restrict__ deg,
        int* __restrict__ bsum, int N) {
    __shared__ int sd[256];
    int t = threadIdx.x, n = blockIdx.x * 256 + t;
    sd[t] = (n < N) ? deg[n] : 0;
    __syncthreads();
    for (int o = 128; o; o >>= 1) {
        if (t < o) sd[t] += sd[t + o];
        __syncthreads();
    }
    if (!t) bsum[blockIdx.x] = sd[0];
}

// scanB: exclusive scan of block sums (nb <= 256), single block
__global__ __launch_bounds__(256) void tm_scanB(const int* __restrict__ bsum,
        int* __restrict__ boff, int nb) {
    __shared__ int sd[256];
    int t = threadIdx.x;
    int v = (t < nb) ? bsum[t] : 0;
    sd[t] = v;
    __syncthreads();
    for (int o = 1; o < 256; o <<= 1) {
        int x = (t >= o) ? sd[t - o] : 0;
        __syncthreads();
        sd[t] += x;
        __syncthreads();
    }
    if (t < nb) boff[t] = sd[t] - v;   // exclusive
}

// scanC: per-element exclusive offsets; off[N]=E; cursor=off copy
__global__ __launch_bounds__(256) void tm_scanC(const int* __restrict__ deg,
        const int* __restrict__ boff, int* __restrict__ off,
        int* __restrict__ cursor, int N) {
    __shared__ int sd[256];
    int t = threadIdx.x, n = blockIdx.x * 256 + t;
    int v = (n < N) ? deg[n] : 0;
    sd[t] = v;
    __syncthreads();
    for (int o = 1; o < 256; o <<= 1) {
        int x = (t >= o) ? sd[t - o] : 0;
        __syncthreads();
        sd[t] += x;
        __syncthreads();
    }
    if (n < N) {
        int ex = boff[blockIdx.x] + sd[t] - v;
        off[n] = ex;
        cursor[n] = ex;
        if (n == N - 1) off[N] = ex + v;
    }
}

// K_scatter: perm[pos] = {src, e} grouped by dst
__global__ __launch_bounds__(256) void tm_scatter(const int* __restrict__ ei,
        int* __restrict__ cursor, int2* __restrict__ perm, int E) {
    int e = blockIdx.x * 256 + threadIdx.x;
    if (e >= E) return;
    int src = ei[e];
    int dst = ei[E + e];
    int pos = atomicAdd(&cursor[dst], 1);
    perm[pos] = make_int2(src, e);
}

// K_agg: one block (3 waves = 3 heads) per dst node. Online softmax + weighted
// aggregation fully in registers; writes normalized aggr once. No float atomics.
__global__ __launch_bounds__(192) void tm_agg(const int2* __restrict__ perm,
        const int* __restrict__ off, const float* __restrict__ ea,
        const float* __restrict__ We, const float* __restrict__ u,
        const float* __restrict__ sA, const float* __restrict__ xp,
        float* __restrict__ aggrN, int N) {
    const int n = blockIdx.x;
    const int t = threadIdx.x;
    const int h = t >> 6, lane = t & 63;
    float wcol[ECC], uh[ECC];
    #pragma unroll
    for (int k = 0; k < ECC; ++k)
        wcol[k] = We[k * HCdim + h * CC + lane];
    #pragma unroll
    for (int k = 0; k < ECC; ++k)
        uh[k] = u[h * ECC + k];
    const float s0 = sA[(size_t)n * 8 + h];
    const int start = off[n], end = off[n + 1];
    float m = -3.0e38f, s = 0.f, acc = 0.f;
    for (int pos = start; pos < end; ++pos) {
        const int2 pe = perm[pos];
        const int src = pe.x;
        const float4* p4 = (const float4*)(ea + (size_t)pe.y * ECC);
        float d = 0.f, ep = 0.f;
        #pragma unroll
        for (int q = 0; q < 8; ++q) {
            float4 v = p4[q];
            d  = fmaf(v.x, uh[4*q],       d);
            d  = fmaf(v.y, uh[4*q + 1],   d);
            d  = fmaf(v.z, uh[4*q + 2],   d);
            d  = fmaf(v.w, uh[4*q + 3],   d);
            ep = fmaf(v.x, wcol[4*q],     ep);
            ep = fmaf(v.y, wcol[4*q + 1], ep);
            ep = fmaf(v.z, wcol[4*q + 2], ep);
            ep = fmaf(v.w, wcol[4*q + 3], ep);
        }
        float a = s0 + d + sA[(size_t)src * 8 + 4 + h];
        a = (a >= 0.f) ? a : NEG_SLOPE * a;
        float p;
        if (a > m) {               // wave-uniform branch
            float r = __expf(m - a);
            s *= r;
            acc *= r;
            m = a;
            p = 1.f;
        } else {
            p = __expf(a - m);
        }
        s += p;
        const float xj = xp[(size_t)src * HCdim + h * CC + lane];
        acc = fmaf(p * ep, xj, acc);
    }
    const float inv = 1.f / (s + 1e-16f);
    aggrN[(size_t)n * HCdim + h * CC + lane] = acc * inv;
}

// K5: out[n,:] = aggrN[n,:] @ Ws + bias   (aggrN already normalized)
__global__ __launch_bounds__(256) void tm_k5(const float* __restrict__ aggrN,
        const float* __restrict__ Ws, const float* __restrict__ bias,
        float* __restrict__ out, int N) {
    __shared__ float wsl[HCdim * CC];   // 48 KiB
    __shared__ float al[4][HCdim];
    const int t = threadIdx.x;
    const int wv = t >> 6, lane = t & 63;
    for (int i = t; i < HCdim * CC; i += 256) wsl[i] = Ws[i];
    const float b = bias[lane];
    for (int base = blockIdx.x * 4; base < N; base += gridDim.x * 4) {
        const int n = base + wv;
        __syncthreads();
        if (n < N) {
            for (int i = lane; i < HCdim; i += 64)
                al[wv][i] = aggrN[(size_t)n * HCdim + i];
        }
        __syncthreads();
        if (n < N) {
            float acc = b;
            #pragma unroll
            for (int k = 0; k < HCdim; ++k)
                acc = fmaf(al[wv][k], wsl[k * CC + lane], acc);
            out[(size_t)n * CC + lane] = acc;
        }
    }
}

extern "C" void kernel_launch(void* const* d_in, const int* in_sizes, int n_in,
                              void* d_out, int out_size, void* d_ws, size_t ws_size,
                              hipStream_t stream) {
    const float* x    = (const float*)d_in[0];
    const int*   ei   = (const int*)d_in[1];
    const float* ea   = (const float*)d_in[2];
    const float* Wn   = (const float*)d_in[3];
    const float* We   = (const float*)d_in[4];
    const float* wt   = (const float*)d_in[5];
    const float* Ws   = (const float*)d_in[6];
    const float* bias = (const float*)d_in[7];
    float* out = (float*)d_out;
    const int N = in_sizes[0] / CC;
    const int E = in_sizes[1] / 2;
    const int nb = (N + 255) / 256;          // scan blocks (<= 256)

    // workspace layout (floats; keep 8B alignment for int2 perm)
    float* ws = (float*)d_ws;
    size_t o = 0;
    float* xp = ws + o;                  o += (size_t)N * HCdim;   // 38.4 MB
    float* sA = ws + o;                  o += (size_t)N * 8;       // 1.6 MB
    float* u  = ws + o;                  o += 128;
    int2*  perm = (int2*)(ws + o);       o += (size_t)E * 2;       // 6.4 MB
    int* deg    = (int*)(ws + o);        o += N;
    int* off    = (int*)(ws + o);        o += N + 1;
    int* cursor = (int*)(ws + o);        o += N;
    int* bsum   = (int*)(ws + o);        o += 256;
    int* boff   = (int*)(ws + o);        o += 256;
    o += (o & 1);                        // realign to 8B
    float* aggrN = ws + o;               o += (size_t)N * HCdim;   // 38.4 MB
    (void)ws_size; (void)n_in; (void)out_size;

    hipMemsetAsync(deg, 0, (size_t)N * sizeof(int), stream);

    tm_k0<<<1, 96, 0, stream>>>(We, wt, u);
    tm_k1<<<(N + K1_ROWS - 1) / K1_ROWS, 192, 0, stream>>>(x, Wn, wt, xp, sA, N);
    tm_deg<<<(E + 255) / 256, 256, 0, stream>>>(ei, deg, E);
    tm_scanA<<<nb, 256, 0, stream>>>(deg, bsum, N);
    tm_scanB<<<1, 256, 0, stream>>>(bsum, boff, nb);
    tm_scanC<<<nb, 256, 0, stream>>>(deg, boff, off, cursor, N);
    tm_scatter<<<(E + 255) / 256, 256, 0, stream>>>(ei, cursor, perm, E);
    tm_agg<<<N, 192, 0, stream>>>(perm, off, ea, We, u, sA, xp, aggrN, N);
    tm_k5<<<2048, 256, 0, stream>>>(aggrN, Ws, bias, out, N);
}

// Round 4
// 550.326 us; speedup vs baseline: 2.0639x; 1.1430x over previous
//
#include <hip/hip_runtime.h>

#define CC    64
#define HH    3
#define ECC   32
#define HCdim 192
#define NEG_SLOPE 0.2f

// ---- float <-> monotone uint key (for atomicMax on floats) ----
__device__ __forceinline__ unsigned fkey(float f) {
    int i = __float_as_int(f);
    return (i < 0) ? ~((unsigned)i) : (((unsigned)i) | 0x80000000u);
}
__device__ __forceinline__ float funkey(unsigned k) {
    int i = (k & 0x80000000u) ? (int)(k ^ 0x80000000u) : ~((int)k);
    return __int_as_float(i);
}

// K0: u[h*32+k] = sum_c We[k*192 + h*64 + c] * wt[h*192 + 64 + c]
__global__ void tm_k0(const float* __restrict__ We, const float* __restrict__ wt,
                      float* __restrict__ u) {
    int t = threadIdx.x;
    if (t >= HH * ECC) return;
    int h = t >> 5, k = t & 31;
    float s = 0.f;
    #pragma unroll
    for (int c = 0; c < CC; ++c)
        s = fmaf(We[k * HCdim + h * CC + c], wt[h * HCdim + CC + c], s);
    u[t] = s;
}

// K1: xp = x @ Wn (N x 64 @ 64 x 192), fused per-node attention scalars:
//     sA[n*8+h]   = xp[n,h,:] . w0[h]   (x_i part, keyed by dst)
//     sA[n*8+4+h] = xp[n,h,:] . w2[h]   (x_j part, keyed by src)
#define K1_ROWS 64
__global__ __launch_bounds__(192) void tm_k1(const float* __restrict__ x,
        const float* __restrict__ Wn, const float* __restrict__ wt,
        float* __restrict__ xp, float* __restrict__ sA, int N) {
    __shared__ float wl[CC * HCdim];     // 48 KiB
    __shared__ float xl[K1_ROWS * CC];   // 16 KiB
    const int t = threadIdx.x;
    const int h = t >> 6, c = t & 63;
    for (int i = t; i < CC * HCdim; i += 192) wl[i] = Wn[i];
    const float w0c = wt[h * HCdim + c];
    const float w2c = wt[h * HCdim + 2 * CC + c];
    const int base = blockIdx.x * K1_ROWS;
    const int rows = min(K1_ROWS, N - base);
    for (int i = t; i < rows * CC; i += 192) xl[i] = x[(size_t)base * CC + i];
    __syncthreads();
    for (int r = 0; r < rows; ++r) {
        float v = 0.f;
        #pragma unroll
        for (int k = 0; k < CC; ++k)
            v = fmaf(xl[r * CC + k], wl[k * HCdim + t], v);
        const int n = base + r;
        xp[(size_t)n * HCdim + t] = v;
        float a0 = v * w0c, a2 = v * w2c;
        #pragma unroll
        for (int off = 32; off; off >>= 1) {
            a0 += __shfl_xor(a0, off);
            a2 += __shfl_xor(a2, off);
        }
        if (c == 0) {
            sA[n * 8 + h]     = a0;
            sA[n * 8 + 4 + h] = a2;
        }
    }
}

// K_deg: degree histogram over dst
__global__ __launch_bounds__(256) void tm_deg(const int* __restrict__ ei,
        int* __restrict__ deg, int E) {
    int e = blockIdx.x * 256 + threadIdx.x;
    if (e < E) atomicAdd(&deg[ei[E + e]], 1);
}

// scanA: per-block (256) sums of deg
__global__ __launch_bounds__(256) void tm_scanA(const int* __restrict__ deg,
        int* __restrict__ bsum, int N) {
    __shared__ int sd[256];
    int t = threadIdx.x, n = blockIdx.x * 256 + t;
    sd[t] = (n < N) ? deg[n] : 0;
    __syncthreads();
    for (int o = 128; o; o >>= 1) {
        if (t < o) sd[t] += sd[t + o];
        __syncthreads();
    }
    if (!t) bsum[blockIdx.x] = sd[0];
}

// scanB: exclusive scan of block sums (nb <= 256), single block
__global__ __launch_bounds__(256) void tm_scanB(const int* __restrict__ bsum,
        int* __restrict__ boff, int nb) {
    __shared__ int sd[256];
    int t = threadIdx.x;
    int v = (t < nb) ? bsum[t] : 0;
    sd[t] = v;
    __syncthreads();
    for (int o = 1; o < 256; o <<= 1) {
        int x = (t >= o) ? sd[t - o] : 0;
        __syncthreads();
        sd[t] += x;
        __syncthreads();
    }
    if (t < nb) boff[t] = sd[t] - v;   // exclusive
}

// scanC: per-element exclusive offsets; off[N]=E; cursor=off copy
__global__ __launch_bounds__(256) void tm_scanC(const int* __restrict__ deg,
        const int* __restrict__ boff, int* __restrict__ off,
        int* __restrict__ cursor, int N) {
    __shared__ int sd[256];
    int t = threadIdx.x, n = blockIdx.x * 256 + t;
    int v = (n < N) ? deg[n] : 0;
    sd[t] = v;
    __syncthreads();
    for (int o = 1; o < 256; o <<= 1) {
        int x = (t >= o) ? sd[t - o] : 0;
        __syncthreads();
        sd[t] += x;
        __syncthreads();
    }
    if (n < N) {
        int ex = boff[blockIdx.x] + sd[t] - v;
        off[n] = ex;
        cursor[n] = ex;
        if (n == N - 1) off[N] = ex + v;
    }
}

// K_scatter2 (fused old K2 + scatter): per edge -
//   pos = cursor[dst]++; perm[pos] = {src, e};
//   alphaP[pos] = {a0,a1,a2,0} = leaky(s0[dst,h] + ea[e].u[h] + s2[src,h]);
//   atomicMax(segmax[dst*3+h]) so tm_agg needs no online softmax.
__global__ __launch_bounds__(256) void tm_scatter2(const int* __restrict__ ei,
        const float* __restrict__ ea, const float* __restrict__ u,
        const float* __restrict__ sA, int* __restrict__ cursor,
        int2* __restrict__ perm, float4* __restrict__ alphaP,
        unsigned* __restrict__ segmax, int E) {
    __shared__ float ul[HH * ECC];
    const int t = threadIdx.x;
    if (t < HH * ECC) ul[t] = u[t];
    __syncthreads();
    const int e = blockIdx.x * 256 + t;
    if (e >= E) return;
    const int src = ei[e];
    const int dst = ei[E + e];
    float av[ECC];
    const float4* p4 = (const float4*)(ea + (size_t)e * ECC);
    #pragma unroll
    for (int q = 0; q < 8; ++q) {
        float4 v = p4[q];
        av[4*q] = v.x; av[4*q+1] = v.y; av[4*q+2] = v.z; av[4*q+3] = v.w;
    }
    float d0 = 0.f, d1 = 0.f, d2 = 0.f;
    #pragma unroll
    for (int k = 0; k < ECC; ++k) {
        d0 = fmaf(av[k], ul[k], d0);
        d1 = fmaf(av[k], ul[ECC + k], d1);
        d2 = fmaf(av[k], ul[2 * ECC + k], d2);
    }
    const float4 s0 = *(const float4*)(sA + (size_t)dst * 8);
    const float4 s2 = *(const float4*)(sA + (size_t)src * 8 + 4);
    float a0 = s0.x + d0 + s2.x;
    float a1 = s0.y + d1 + s2.y;
    float a2 = s0.z + d2 + s2.z;
    a0 = (a0 >= 0.f) ? a0 : NEG_SLOPE * a0;
    a1 = (a1 >= 0.f) ? a1 : NEG_SLOPE * a1;
    a2 = (a2 >= 0.f) ? a2 : NEG_SLOPE * a2;
    const int pos = atomicAdd(&cursor[dst], 1);
    perm[pos] = make_int2(src, e);
    alphaP[pos] = make_float4(a0, a1, a2, 0.f);
    atomicMax(&segmax[dst * 3 + 0], fkey(a0));
    atomicMax(&segmax[dst * 3 + 1], fkey(a1));
    atomicMax(&segmax[dst * 3 + 2], fkey(a2));
}

// K_agg: one block (3 waves = 3 heads) per dst node. alpha & segmax precomputed,
// so the loop is branch-free: p=exp(a-m); s+=p; ep=ea.wcol; acc+=p*ep*xj.
__global__ __launch_bounds__(192) void tm_agg(const int2* __restrict__ perm,
        const int* __restrict__ off, const float* __restrict__ ea,
        const float* __restrict__ We, const float* __restrict__ alphaP,
        const unsigned* __restrict__ segmax, const float* __restrict__ xp,
        float* __restrict__ aggrN, int N) {
    const int n = blockIdx.x;
    const int t = threadIdx.x;
    const int h = t >> 6, lane = t & 63;
    float wcol[ECC];
    #pragma unroll
    for (int k = 0; k < ECC; ++k)
        wcol[k] = We[k * HCdim + h * CC + lane];
    const float m = funkey(segmax[n * 3 + h]);
    const int start = off[n], end = off[n + 1];
    float s = 0.f, acc = 0.f;
    for (int pos = start; pos < end; ++pos) {
        const int2 pe = perm[pos];
        const int src = __builtin_amdgcn_readfirstlane(pe.x);
        const int eid = __builtin_amdgcn_readfirstlane(pe.y);
        const float a = alphaP[(size_t)pos * 4 + h];
        const float p = __expf(a - m);
        s += p;
        const float4* p4 = (const float4*)(ea + (size_t)eid * ECC);
        float ep = 0.f;
        #pragma unroll
        for (int q = 0; q < 8; ++q) {
            float4 v = p4[q];
            ep = fmaf(v.x, wcol[4*q],     ep);
            ep = fmaf(v.y, wcol[4*q + 1], ep);
            ep = fmaf(v.z, wcol[4*q + 2], ep);
            ep = fmaf(v.w, wcol[4*q + 3], ep);
        }
        const float xj = xp[(size_t)src * HCdim + h * CC + lane];
        acc = fmaf(p * ep, xj, acc);
    }
    aggrN[(size_t)n * HCdim + h * CC + lane] = acc / (s + 1e-16f);
}

// K5: out[n,:] = aggrN[n,:] @ Ws + bias   (aggrN already normalized)
__global__ __launch_bounds__(256) void tm_k5(const float* __restrict__ aggrN,
        const float* __restrict__ Ws, const float* __restrict__ bias,
        float* __restrict__ out, int N) {
    __shared__ float wsl[HCdim * CC];   // 48 KiB
    __shared__ float al[4][HCdim];
    const int t = threadIdx.x;
    const int wv = t >> 6, lane = t & 63;
    for (int i = t; i < HCdim * CC; i += 256) wsl[i] = Ws[i];
    const float b = bias[lane];
    for (int base = blockIdx.x * 4; base < N; base += gridDim.x * 4) {
        const int n = base + wv;
        __syncthreads();
        if (n < N) {
            for (int i = lane; i < HCdim; i += 64)
                al[wv][i] = aggrN[(size_t)n * HCdim + i];
        }
        __syncthreads();
        if (n < N) {
            float acc = b;
            #pragma unroll
            for (int k = 0; k < HCdim; ++k)
                acc = fmaf(al[wv][k], wsl[k * CC + lane], acc);
            out[(size_t)n * CC + lane] = acc;
        }
    }
}

extern "C" void kernel_launch(void* const* d_in, const int* in_sizes, int n_in,
                              void* d_out, int out_size, void* d_ws, size_t ws_size,
                              hipStream_t stream) {
    const float* x    = (const float*)d_in[0];
    const int*   ei   = (const int*)d_in[1];
    const float* ea   = (const float*)d_in[2];
    const float* Wn   = (const float*)d_in[3];
    const float* We   = (const float*)d_in[4];
    const float* wt   = (const float*)d_in[5];
    const float* Ws   = (const float*)d_in[6];
    const float* bias = (const float*)d_in[7];
    float* out = (float*)d_out;
    const int N = in_sizes[0] / CC;
    const int E = in_sizes[1] / 2;
    const int nb = (N + 255) / 256;          // scan blocks (<= 256)

    // workspace layout (floats; 16B alignment kept for float4/int2 buffers)
    float* ws = (float*)d_ws;
    size_t o = 0;
    float* xp = ws + o;                  o += (size_t)N * HCdim;   // 38.4 MB
    float* sA = ws + o;                  o += (size_t)N * 8;       // 1.6 MB
    float* u  = ws + o;                  o += 128;
    float4* alphaP = (float4*)(ws + o);  o += (size_t)E * 4;       // 12.8 MB
    int2*  perm = (int2*)(ws + o);       o += (size_t)E * 2;       // 6.4 MB
    int* deg    = (int*)(ws + o);        o += N;
    unsigned* segmax = (unsigned*)(ws + o); o += (size_t)N * HH;
    int* off    = (int*)(ws + o);        o += N + 1;
    int* cursor = (int*)(ws + o);        o += N;
    int* bsum   = (int*)(ws + o);        o += 256;
    int* boff   = (int*)(ws + o);        o += 256;
    o += (4 - (o & 3)) & 3;              // realign
    float* aggrN = ws + o;               o += (size_t)N * HCdim;   // 38.4 MB
    (void)ws_size; (void)n_in; (void)out_size;

    // zero deg + segmax (adjacent)
    (void)hipMemsetAsync(deg, 0, (size_t)N * (1 + HH) * sizeof(int), stream);

    tm_k0<<<1, 96, 0, stream>>>(We, wt, u);
    tm_k1<<<(N + K1_ROWS - 1) / K1_ROWS, 192, 0, stream>>>(x, Wn, wt, xp, sA, N);
    tm_deg<<<(E + 255) / 256, 256, 0, stream>>>(ei, deg, E);
    tm_scanA<<<nb, 256, 0, stream>>>(deg, bsum, N);
    tm_scanB<<<1, 256, 0, stream>>>(bsum, boff, nb);
    tm_scanC<<<nb, 256, 0, stream>>>(deg, boff, off, cursor, N);
    tm_scatter2<<<(E + 255) / 256, 256, 0, stream>>>(ei, ea, u, sA, cursor,
                                                     perm, alphaP, segmax, E);
    tm_agg<<<N, 192, 0, stream>>>(perm, off, ea, We, (const float*)alphaP,
                                  segmax, xp, aggrN, N);
    tm_k5<<<2048, 256, 0, stream>>>(aggrN, Ws, bias, out, N);
}